// Round 9
// baseline (216.110 us; speedup 1.0000x reference)
//
#include <hip/hip_runtime.h>
#include <math.h>

#define VOCABN 32000
#define EMBEDN 256
#define HIDN   256
#define BN     32
#define SN     4096
#define CH     32           // steps per chunk
#define WU     16           // warm-up: f <= ~0.53 -> 0.53^16 ~ 4e-5 carry-in err (validated R3-R8)
#define NCHUNK (SN / CH)    // 128

typedef __attribute__((ext_vector_type(8))) _Float16 half8;
typedef __attribute__((ext_vector_type(4))) _Float16 half4;
typedef __attribute__((ext_vector_type(4))) float f32x4;

#define EBS 520             // epilogue LDS row stride (halves): 1040 B -> groups 16 banks apart

// ---------------------------------------------------------------------------
// Kernel A: table GEMM. emb fp32 staged through LDS w/ inline cvt; cw fp32
// loaded directly, converted in registers (no cvt kernel needed — full-line
// stores below remove the L2 merge-window sensitivity that killed this in R8).
// Block = 64 vocab rows x ALL 512 outputs, 8 waves = 2(v) x 4(c strips);
// wave tile 32v x 128c, acc 64 VGPR, launch_bounds(512,4) -> 2 blocks/CU.
//
// R8 lesson (counters): the old epilogue issued 64 scalar 2-byte scattered
// stores/thread (16.4M store instr total) = store-issue-bound, and its
// half-line writes doubled WRITE_SIZE when L2 evicted early. New epilogue:
// activation -> ds_write_b16 into a 64x520 LDS tile -> barrier -> 8 coalesced
// global_store_dwordx4 per thread (8x fewer stores, all full-line).
// Output interleaved: zf[v][2c]=tanh(z), zf[v][2c+1]=sigmoid(f).
// ---------------------------------------------------------------------------
__global__ __launch_bounds__(512, 4)
void build_tab_kernel(const float* __restrict__ emb, const float* __restrict__ cw,
                      const float* __restrict__ cb, _Float16* __restrict__ zf) {
    __shared__ _Float16 sh[64 * EBS];     // 66.6 KB; K-loop uses first 64*264 as A-tile

    const int t = threadIdx.x, lane = t & 63, w = t >> 6;
    const int wv   = w >> 2;              // vocab half (0/1) -> 32 rows
    const int wc   = w & 3;               // col strip 0..3
    const int gate = wc >> 1;             // 0 = z, 1 = f
    const int chb  = (wc & 1) * 128;      // channel base within gate
    const int v0   = blockIdx.x * 64;
    const int lrow = lane & 15, ko = (lane >> 4) * 8;

    // ---- stage A tile (inline fp32->fp16), stride 264, 8 float4 per thread ----
    #pragma unroll
    for (int i = 0; i < 8; ++i) {
        const int idx = t + i * 512;          // 0..4095 (64 float4 per row)
        const int row = idx >> 6;
        const int k4  = (idx & 63) * 4;
        float4 a = *(const float4*)(emb + (size_t)(v0 + row) * EMBEDN + k4);
        half4 h;
        h[0] = (_Float16)a.x; h[1] = (_Float16)a.y;
        h[2] = (_Float16)a.z; h[3] = (_Float16)a.w;
        *(half4*)(sh + row * 264 + k4) = h;
    }

    const float* Bb = cw + (size_t)(gate * 256 + chb + lrow) * EMBEDN + ko;

    f32x4 acc[2][8];
    #pragma unroll
    for (int i = 0; i < 2; ++i)
        #pragma unroll
        for (int j = 0; j < 8; ++j) acc[i][j] = (f32x4)0.f;

    __syncthreads();

    #pragma unroll
    for (int k = 0; k < 8; ++k) {
        half8 fb[8];
        #pragma unroll
        for (int j = 0; j < 8; ++j) {
            const float4 x0 = *(const float4*)(Bb + (size_t)j * 16 * EMBEDN + k * 32);
            const float4 x1 = *(const float4*)(Bb + (size_t)j * 16 * EMBEDN + k * 32 + 4);
            fb[j][0] = (_Float16)x0.x; fb[j][1] = (_Float16)x0.y;
            fb[j][2] = (_Float16)x0.z; fb[j][3] = (_Float16)x0.w;
            fb[j][4] = (_Float16)x1.x; fb[j][5] = (_Float16)x1.y;
            fb[j][6] = (_Float16)x1.z; fb[j][7] = (_Float16)x1.w;
        }
        half8 fa[2];
        #pragma unroll
        for (int i = 0; i < 2; ++i)
            fa[i] = *(const half8*)(sh + (wv * 32 + i * 16 + lrow) * 264 + k * 32 + ko);
        #pragma unroll
        for (int i = 0; i < 2; ++i)
            #pragma unroll
            for (int j = 0; j < 8; ++j)
                acc[i][j] = __builtin_amdgcn_mfma_f32_16x16x32_f16(fa[i], fb[j], acc[i][j], 0, 0, 0);
    }

    __syncthreads();                      // A-tile LDS about to be reused as epilogue buffer

    // ---- epilogue pass 1: activation -> LDS tile [v][2ch+gate] (2-way banks max) ----
    #pragma unroll
    for (int j = 0; j < 8; ++j) {
        const int ch = chb + j * 16 + lrow;
        const float bias = cb[gate * HIDN + ch];
        #pragma unroll
        for (int i = 0; i < 2; ++i) {
            const int vr = wv * 32 + i * 16 + (lane >> 4) * 4;
            #pragma unroll
            for (int r = 0; r < 4; ++r) {
                const float x = acc[i][j][r] + bias;
                float val;
                if (gate == 0) { float e = __expf(2.f * x); val = (e - 1.f) / (e + 1.f); }
                else           { val = 1.f / (1.f + __expf(-x)); }
                sh[(vr + r) * EBS + 2 * ch + gate] = (_Float16)val;
            }
        }
    }

    __syncthreads();

    // ---- epilogue pass 2: coalesced full-line stores (8 dwordx4 per thread) ----
    #pragma unroll
    for (int it = 0; it < 8; ++it) {
        const int idx = t + it * 512;         // 64 rows x 64 16B-chunks
        const int row = idx >> 6;
        const int ck  = idx & 63;
        half8 v = *(const half8*)(sh + row * EBS + ck * 8);
        *(half8*)(zf + (size_t)(v0 + row) * 512 + ck * 8) = v;
    }
}

// ---------------------------------------------------------------------------
// Kernel B (R8 structure): chunked scan, MFMA (l,q) reduction, fused softmax
// partials. 1 wave per (b, chunk); lane owns 4 channels; 16-deep gather ring
// (slot = step mod 16 -> static register indexing). Every 16 steps: 8 MFMA vs
// constant B (col0=Mu, col1=Wout) -> l,q for 16 steps; lanes n==0 accumulate
// SE=sum(e^l), SQ=sum(e^l q) (no max needed: |l|<=0.15). One per-chunk partial
// store per wave — NO global atomics (R6 lesson).
// ---------------------------------------------------------------------------
__global__ __launch_bounds__(256, 4)
void scan_kernel(const int* __restrict__ X, const _Float16* __restrict__ zf,
                 const float* __restrict__ Mu, const float* __restrict__ Wout,
                 float* __restrict__ pse, float* __restrict__ psq) {
    __shared__ int ids[4][CH + WU];
    __shared__ _Float16 hA[4][16][264];   // per-wave A-tile; stride 264 -> cheap banks

    const int t = threadIdx.x, w = t >> 6, lane = t & 63;
    const int b = blockIdx.y, c = blockIdx.x * 4 + w;
    const int n = lane & 15, kseg = lane >> 4;
    const int sMid = c * CH;
    int sBeg = sMid - WU; if (sBeg < 0) sBeg = 0;
    const int nWarm = sMid - sBeg;        // 0 (chunk 0) or 16
    const int nTot  = nWarm + CH;         // 32 or 48

    for (int i = lane; i < nTot; i += 64) ids[w][i] = X[(size_t)b * SN + sBeg + i];
    __syncthreads();

    // constant B fragments: B[k=ch][col], col0=Mu, col1=Wout, cols 2..15 = 0
    half8 fb[8];
    #pragma unroll
    for (int kc = 0; kc < 8; ++kc) {
        #pragma unroll
        for (int j = 0; j < 8; ++j) {
            const int ch = kc * 32 + kseg * 8 + j;
            float v = 0.f;
            if (n == 0) v = Mu[ch];
            else if (n == 1) v = Wout[ch];
            fb[kc][j] = (_Float16)v;
        }
    }

    const _Float16* base = zf + 8 * lane;  // this lane's 4 {z,f} pairs within a row
    half8 p[16];
    #pragma unroll
    for (int i = 0; i < 16; ++i)
        p[i] = *(const half8*)(base + (size_t)ids[w][i] * 512);

    float h0 = 0.f, h1 = 0.f, h2 = 0.f, h3 = 0.f;
    float se_loc = 0.f, sq_loc = 0.f;
    _Float16* myA = &hA[w][0][0];
    const int nG = nTot >> 4, gWarm = nWarm >> 4;

    for (int gi = 0; gi < nG; ++gi) {
        const bool act = (gi >= gWarm);
        #pragma unroll
        for (int ii = 0; ii < 16; ++ii) {
            const int i = gi * 16 + ii;
            half8 cur = p[ii];            // ring slot == group index (static)
            const int nx = i + 16;
            if (nx < nTot) p[ii] = *(const half8*)(base + (size_t)ids[w][nx] * 512);
            const float z0 = (float)cur[0], f0 = (float)cur[1];
            const float z1 = (float)cur[2], f1 = (float)cur[3];
            const float z2 = (float)cur[4], f2 = (float)cur[5];
            const float z3 = (float)cur[6], f3 = (float)cur[7];
            h0 = z0 + f0 * (h0 - z0);
            h1 = z1 + f1 * (h1 - z1);
            h2 = z2 + f2 * (h2 - z2);
            h3 = z3 + f3 * (h3 - z3);
            if (act) {
                half4 hh;
                hh[0] = (_Float16)h0; hh[1] = (_Float16)h1;
                hh[2] = (_Float16)h2; hh[3] = (_Float16)h3;
                *(half4*)(myA + ii * 264 + 4 * lane) = hh;
            }
        }
        if (act) {
            f32x4 a4 = (f32x4)0.f;
            #pragma unroll
            for (int kc = 0; kc < 8; ++kc) {
                half8 fa = *(const half8*)(myA + n * 264 + kc * 32 + kseg * 8);
                a4 = __builtin_amdgcn_mfma_f32_16x16x32_f16(fa, fb[kc], a4, 0, 0, 0);
            }
            // lanes n==0 hold l, lanes n==1 hold q for the same 4 steps -> swap
            #pragma unroll
            for (int r = 0; r < 4; ++r) {
                const float other = __shfl_xor(a4[r], 1);   // for n==0: q
                if (n == 0) {
                    const float e = __expf(a4[r]);
                    se_loc += e;
                    sq_loc += e * other;
                }
            }
        }
    }

    // partials live in lanes 0,16,32,48 -> 2-level fold, one store per wave
    se_loc += __shfl_xor(se_loc, 16); se_loc += __shfl_xor(se_loc, 32);
    sq_loc += __shfl_xor(sq_loc, 16); sq_loc += __shfl_xor(sq_loc, 32);
    if (lane == 0) {
        pse[(size_t)b * NCHUNK + c] = se_loc;
        psq[(size_t)b * NCHUNK + c] = sq_loc;
    }
}

// ---------------------------------------------------------------------------
// Kernel C: finalize — reduce 128 per-chunk partials per batch.
// out[b] = sum(SQ)/sum(SE) + b_out
// ---------------------------------------------------------------------------
__global__ __launch_bounds__(128)
void finalize_kernel(const float* __restrict__ pse, const float* __restrict__ psq,
                     const float* __restrict__ bout, float* __restrict__ out) {
    __shared__ float s_se[2], s_sq[2];
    const int b = blockIdx.x, t = threadIdx.x, w = t >> 6, lane = t & 63;
    float se = pse[(size_t)b * NCHUNK + t];
    float sq = psq[(size_t)b * NCHUNK + t];
    #pragma unroll
    for (int off = 32; off; off >>= 1) { se += __shfl_xor(se, off); sq += __shfl_xor(sq, off); }
    if (lane == 0) { s_se[w] = se; s_sq[w] = sq; }
    __syncthreads();
    if (t == 0) out[b] = (s_sq[0] + s_sq[1]) / (s_se[0] + s_se[1]) + bout[0];
}

// ---------------------------------------------------------------------------
extern "C" void kernel_launch(void* const* d_in, const int* in_sizes, int n_in,
                              void* d_out, int out_size, void* d_ws, size_t ws_size,
                              hipStream_t stream) {
    const int*   X    = (const int*)d_in[0];
    const float* emb  = (const float*)d_in[1];
    const float* cw   = (const float*)d_in[2];
    const float* cb   = (const float*)d_in[3];
    const float* Mu   = (const float*)d_in[4];
    const float* Wout = (const float*)d_in[5];
    const float* bout = (const float*)d_in[6];
    float* out = (float*)d_out;

    // workspace layout (all 16B-aligned)
    _Float16* zf  = (_Float16*)d_ws;                           // 32000*512 = 32.768 MB
    float*    pse = (float*)(zf + (size_t)VOCABN * 512);       // 32*128 floats
    float*    psq = pse + BN * NCHUNK;                         // 32*128 floats

    build_tab_kernel<<<VOCABN / 64, 512, 0, stream>>>(emb, cw, cb, zf);
    scan_kernel<<<dim3(NCHUNK / 4, BN), 256, 0, stream>>>(X, zf, Mu, Wout, pse, psq);
    finalize_kernel<<<BN, 128, 0, stream>>>(pse, psq, bout, out);
}

// Round 10
// 169.495 us; speedup vs baseline: 1.2750x; 1.2750x over previous
//
#include <hip/hip_runtime.h>
#include <math.h>

#define VOCABN 32000
#define EMBEDN 256
#define HIDN   256
#define BN     32
#define SN     4096
#define CH     32           // steps per chunk
#define WU     16           // warm-up: f <= ~0.53 -> 0.53^16 ~ 4e-5 carry-in err (validated R3-R9)
#define NCHUNK (SN / CH)    // 128

typedef __attribute__((ext_vector_type(8))) _Float16 half8;
typedef __attribute__((ext_vector_type(4))) _Float16 half4;
typedef __attribute__((ext_vector_type(4))) float f32x4;

// ---------------------------------------------------------------------------
// Kernel 0: fp32 -> fp16 convert for conv_w (512x256, tiny, L2-hot afterwards).
// MEASURED LESSON (R7 48us vs R8 89.5us): loading B as fp32 in build doubles
// the streamed bytes through the dirty L3 and costs ~40us — keep B fp16.
// ---------------------------------------------------------------------------
__global__ __launch_bounds__(256)
void cvt_kernel(const float* __restrict__ s, _Float16* __restrict__ d, int n8) {
    const int i = blockIdx.x * 256 + threadIdx.x;
    if (i < n8) {
        const float4 a = ((const float4*)s)[2 * i];
        const float4 b = ((const float4*)s)[2 * i + 1];
        half8 h;
        h[0] = (_Float16)a.x; h[1] = (_Float16)a.y; h[2] = (_Float16)a.z; h[3] = (_Float16)a.w;
        h[4] = (_Float16)b.x; h[5] = (_Float16)b.y; h[6] = (_Float16)b.z; h[7] = (_Float16)b.w;
        ((half8*)d)[i] = h;
    }
}

// ---------------------------------------------------------------------------
// Kernel A: table GEMM (R7-validated config, smaller tile for more MLP).
// Block = 32 vocab rows x ALL 512 outputs, 4 waves = 4 col strips;
// wave tile 32v x 128c, acc[2][8]=64 VGPR; launch_bounds(256,4) -> cap 128
// VGPR -> 4 blocks/CU resident (2x R7's per-CU outstanding misses; build is
// throttled by the dirty-L3 allocate/evict regime at ~1.2 TB/s, so more
// in-flight misses per CU is the only internal lever).
// Epilogue: scattered interleaved fp16 stores (R9 measured: LDS-transpose
// epilogue was NOT better). Output: zf[v][2c]=tanh(z), zf[v][2c+1]=sigmoid(f).
// ---------------------------------------------------------------------------
__global__ __launch_bounds__(256, 4)
void build_tab_kernel(const float* __restrict__ emb, const _Float16* __restrict__ cwh,
                      const float* __restrict__ cb, _Float16* __restrict__ zf) {
    __shared__ _Float16 As[32 * 264];     // 16.9 KB; stride 264 halves -> <=2-way banks

    const int t = threadIdx.x, lane = t & 63, w = t >> 6;   // w = col strip 0..3
    const int gate = w >> 1;              // 0 = z, 1 = f
    const int chb  = (w & 1) * 128;       // channel base within gate
    const int v0   = blockIdx.x * 32;
    const int lrow = lane & 15, ko = (lane >> 4) * 8;

    // ---- stage A tile (inline fp32->fp16): 32 rows x 64 float4 = 2048, 8/thread ----
    #pragma unroll
    for (int i = 0; i < 8; ++i) {
        const int idx = t + i * 256;          // 0..2047
        const int row = idx >> 6;
        const int k4  = (idx & 63) * 4;
        float4 a = *(const float4*)(emb + (size_t)(v0 + row) * EMBEDN + k4);
        half4 h;
        h[0] = (_Float16)a.x; h[1] = (_Float16)a.y;
        h[2] = (_Float16)a.z; h[3] = (_Float16)a.w;
        *(half4*)(As + row * 264 + k4) = h;
    }

    const _Float16* Bb = cwh + (size_t)(gate * 256 + chb + lrow) * EMBEDN + ko;

    f32x4 acc[2][8];
    #pragma unroll
    for (int i = 0; i < 2; ++i)
        #pragma unroll
        for (int j = 0; j < 8; ++j) acc[i][j] = (f32x4)0.f;

    __syncthreads();                      // the only barrier

    #pragma unroll
    for (int k = 0; k < 8; ++k) {
        half8 fb[8];
        #pragma unroll
        for (int j = 0; j < 8; ++j)
            fb[j] = *(const half8*)(Bb + (size_t)j * 16 * EMBEDN + k * 32);
        half8 fa[2];
        #pragma unroll
        for (int i = 0; i < 2; ++i)
            fa[i] = *(const half8*)(As + (i * 16 + lrow) * 264 + k * 32 + ko);
        #pragma unroll
        for (int i = 0; i < 2; ++i)
            #pragma unroll
            for (int j = 0; j < 8; ++j)
                acc[i][j] = __builtin_amdgcn_mfma_f32_16x16x32_f16(fa[i], fb[j], acc[i][j], 0, 0, 0);
    }

    // ---- epilogue: bias + activation, interleaved fp16 stores (R7-validated) ----
    #pragma unroll
    for (int j = 0; j < 8; ++j) {
        const int ch = chb + j * 16 + lrow;
        const float bias = cb[gate * HIDN + ch];
        #pragma unroll
        for (int i = 0; i < 2; ++i) {
            const int vr = v0 + i * 16 + (lane >> 4) * 4;
            #pragma unroll
            for (int r = 0; r < 4; ++r) {
                const float x = acc[i][j][r] + bias;
                float val;
                if (gate == 0) { float e = __expf(2.f * x); val = (e - 1.f) / (e + 1.f); }
                else           { val = 1.f / (1.f + __expf(-x)); }
                zf[(size_t)(vr + r) * 512 + 2 * ch + gate] = (_Float16)val;
            }
        }
    }
}

// ---------------------------------------------------------------------------
// Kernel B: chunked scan, 1 WAVE per block (64 thr) -> ZERO barriers (the DS
// pipe is in-order within a wave, so ids/hA write->read hazards are safe).
// Grid 4096 blocks; lane owns 4 channels; 16-deep static gather ring.
// Every 16 steps: 8 MFMA vs constant B (col0=Mu, col1=Wout) -> l,q for 16
// steps; lanes n==0 accumulate SE=sum(e^l), SQ=sum(e^l q) (no max: |l|<=0.15).
// One per-chunk partial store per wave — NO global atomics (R6 lesson).
// ---------------------------------------------------------------------------
__global__ __launch_bounds__(64, 4)
void scan_kernel(const int* __restrict__ X, const _Float16* __restrict__ zf,
                 const float* __restrict__ Mu, const float* __restrict__ Wout,
                 float* __restrict__ pse, float* __restrict__ psq) {
    __shared__ int ids[CH + WU];
    __shared__ _Float16 hA[16 * 264];     // stride 264 -> cheap banks

    const int lane = threadIdx.x;
    const int c = blockIdx.x, b = blockIdx.y;
    const int n = lane & 15, kseg = lane >> 4;
    const int sMid = c * CH;
    int sBeg = sMid - WU; if (sBeg < 0) sBeg = 0;
    const int nWarm = sMid - sBeg;        // 0 (chunk 0) or 16
    const int nTot  = nWarm + CH;         // 32 or 48

    for (int i = lane; i < nTot; i += 64) ids[i] = X[(size_t)b * SN + sBeg + i];
    // no barrier: single wave, DS ops in-order

    // constant B fragments: B[k=ch][col], col0=Mu, col1=Wout, cols 2..15 = 0
    half8 fb[8];
    #pragma unroll
    for (int kc = 0; kc < 8; ++kc) {
        #pragma unroll
        for (int j = 0; j < 8; ++j) {
            const int ch = kc * 32 + kseg * 8 + j;
            float v = 0.f;
            if (n == 0) v = Mu[ch];
            else if (n == 1) v = Wout[ch];
            fb[kc][j] = (_Float16)v;
        }
    }

    const _Float16* base = zf + 8 * lane;  // this lane's 4 {z,f} pairs within a row
    half8 p[16];
    #pragma unroll
    for (int i = 0; i < 16; ++i)
        p[i] = *(const half8*)(base + (size_t)ids[i] * 512);

    float h0 = 0.f, h1 = 0.f, h2 = 0.f, h3 = 0.f;
    float se_loc = 0.f, sq_loc = 0.f;
    const int nG = nTot >> 4, gWarm = nWarm >> 4;

    for (int gi = 0; gi < nG; ++gi) {
        const bool act = (gi >= gWarm);
        #pragma unroll
        for (int ii = 0; ii < 16; ++ii) {
            const int i = gi * 16 + ii;
            half8 cur = p[ii];            // ring slot == group index (static)
            const int nx = i + 16;
            if (nx < nTot) p[ii] = *(const half8*)(base + (size_t)ids[nx] * 512);
            const float z0 = (float)cur[0], f0 = (float)cur[1];
            const float z1 = (float)cur[2], f1 = (float)cur[3];
            const float z2 = (float)cur[4], f2 = (float)cur[5];
            const float z3 = (float)cur[6], f3 = (float)cur[7];
            h0 = z0 + f0 * (h0 - z0);
            h1 = z1 + f1 * (h1 - z1);
            h2 = z2 + f2 * (h2 - z2);
            h3 = z3 + f3 * (h3 - z3);
            if (act) {
                half4 hh;
                hh[0] = (_Float16)h0; hh[1] = (_Float16)h1;
                hh[2] = (_Float16)h2; hh[3] = (_Float16)h3;
                *(half4*)(hA + ii * 264 + 4 * lane) = hh;
            }
        }
        if (act) {
            f32x4 a4 = (f32x4)0.f;
            #pragma unroll
            for (int kc = 0; kc < 8; ++kc) {
                half8 fa = *(const half8*)(hA + n * 264 + kc * 32 + kseg * 8);
                a4 = __builtin_amdgcn_mfma_f32_16x16x32_f16(fa, fb[kc], a4, 0, 0, 0);
            }
            // lanes n==0 hold l, lanes n==1 hold q for the same 4 steps -> swap
            #pragma unroll
            for (int r = 0; r < 4; ++r) {
                const float other = __shfl_xor(a4[r], 1);   // for n==0: q
                if (n == 0) {
                    const float e = __expf(a4[r]);
                    se_loc += e;
                    sq_loc += e * other;
                }
            }
        }
    }

    // partials live in lanes 0,16,32,48 -> 2-level fold, one store per wave
    se_loc += __shfl_xor(se_loc, 16); se_loc += __shfl_xor(se_loc, 32);
    sq_loc += __shfl_xor(sq_loc, 16); sq_loc += __shfl_xor(sq_loc, 32);
    if (lane == 0) {
        pse[(size_t)b * NCHUNK + c] = se_loc;
        psq[(size_t)b * NCHUNK + c] = sq_loc;
    }
}

// ---------------------------------------------------------------------------
// Kernel C: finalize — reduce 128 per-chunk partials per batch.
// out[b] = sum(SQ)/sum(SE) + b_out
// ---------------------------------------------------------------------------
__global__ __launch_bounds__(128)
void finalize_kernel(const float* __restrict__ pse, const float* __restrict__ psq,
                     const float* __restrict__ bout, float* __restrict__ out) {
    __shared__ float s_se[2], s_sq[2];
    const int b = blockIdx.x, t = threadIdx.x, w = t >> 6, lane = t & 63;
    float se = pse[(size_t)b * NCHUNK + t];
    float sq = psq[(size_t)b * NCHUNK + t];
    #pragma unroll
    for (int off = 32; off; off >>= 1) { se += __shfl_xor(se, off); sq += __shfl_xor(sq, off); }
    if (lane == 0) { s_se[w] = se; s_sq[w] = sq; }
    __syncthreads();
    if (t == 0) out[b] = (s_sq[0] + s_sq[1]) / (s_se[0] + s_se[1]) + bout[0];
}

// ---------------------------------------------------------------------------
extern "C" void kernel_launch(void* const* d_in, const int* in_sizes, int n_in,
                              void* d_out, int out_size, void* d_ws, size_t ws_size,
                              hipStream_t stream) {
    const int*   X    = (const int*)d_in[0];
    const float* emb  = (const float*)d_in[1];
    const float* cw   = (const float*)d_in[2];
    const float* cb   = (const float*)d_in[3];
    const float* Mu   = (const float*)d_in[4];
    const float* Wout = (const float*)d_in[5];
    const float* bout = (const float*)d_in[6];
    float* out = (float*)d_out;

    // workspace layout (all 16B-aligned)
    _Float16* cwh = (_Float16*)d_ws;                           // 512*256   = 0.262 MB
    _Float16* zf  = cwh + (size_t)512 * EMBEDN;                // 32000*512 = 32.768 MB
    float*    pse = (float*)(zf + (size_t)VOCABN * 512);       // 32*128 floats
    float*    psq = pse + BN * NCHUNK;                         // 32*128 floats

    const int nCw8 = 512 * EMBEDN / 8;                         // 16,384
    cvt_kernel<<<(nCw8 + 255) / 256, 256, 0, stream>>>(cw, cwh, nCw8);
    build_tab_kernel<<<VOCABN / 32, 256, 0, stream>>>(emb, cwh, cb, zf);
    scan_kernel<<<dim3(NCHUNK, BN), 64, 0, stream>>>(X, zf, Mu, Wout, pse, psq);
    finalize_kernel<<<BN, 128, 0, stream>>>(pse, psq, bout, out);
}